// Round 3
// baseline (402.428 us; speedup 1.0000x reference)
//
#include <hip/hip_runtime.h>

// QuantizedLinear: out[M=4096, N=11008] = x[M,K=4096] @ (s*(q-zp))[N,K]^T
// Round 3: merged 4-phase schedule (was 8): 32 MFMA per phase, 6 barriers/iter
// (was 16), stage issued after the phase barrier (strict WAR-safe), counted
// vmcnt(4) with re-derived retirement chain. Same LDS swizzle / layout / maps.

#define M_DIM 4096
#define N_DIM 11008
#define K_DIM 4096
#define KT 64              // K_DIM / 64 K-tiles
#define NT_N 43            // N_DIM / 256
#define NT_M 16            // M_DIM / 256

typedef __attribute__((ext_vector_type(8))) short short8;  // 8 x bf16
typedef __attribute__((ext_vector_type(4))) float f32x4;

__device__ inline unsigned short f2bf(float f) {
  unsigned int u = __float_as_uint(f);
  u += 0x7FFFu + ((u >> 16) & 1u);
  return (unsigned short)(u >> 16);
}

// ---- conversion pre-passes ----

__global__ void cvt_w_kernel(const int* __restrict__ q, unsigned short* __restrict__ wb,
                             const float* __restrict__ sp, const float* __restrict__ zpp,
                             int n4) {
  const float s = *sp;
  const float nszp = -s * (*zpp);
  int stride = gridDim.x * blockDim.x;
  for (int i = blockIdx.x * blockDim.x + threadIdx.x; i < n4; i += stride) {
    int4 v = ((const int4*)q)[i];
    ushort4 o = make_ushort4(f2bf(fmaf(s, (float)v.x, nszp)),
                             f2bf(fmaf(s, (float)v.y, nszp)),
                             f2bf(fmaf(s, (float)v.z, nszp)),
                             f2bf(fmaf(s, (float)v.w, nszp)));
    ((ushort4*)wb)[i] = o;
  }
}

__global__ void cvt_x_kernel(const float* __restrict__ x, unsigned short* __restrict__ xb,
                             int n4) {
  int stride = gridDim.x * blockDim.x;
  for (int i = blockIdx.x * blockDim.x + threadIdx.x; i < n4; i += stride) {
    float4 v = ((const float4*)x)[i];
    ushort4 o = make_ushort4(f2bf(v.x), f2bf(v.y), f2bf(v.z), f2bf(v.w));
    ((ushort4*)xb)[i] = o;
  }
}

// ---- 256x256 4-phase GEMM ----
// LDS regions (shorts): A(d,h) = d*32768 + h*8192 ; B(d,h) = d*32768 + 16384 + h*8192
// Half-tile = 128 rows x 64 cols bf16 = 16KB. Swizzle: elem (r,k) at byte
// r*128 + ((k*2) ^ ((r&7)<<4)); staged linearly via global_load_lds with the
// inverse-swizzled global source (verified involution, rounds 1-2).

__device__ __forceinline__ void stage_half(const unsigned short* __restrict__ gsrc,
                                           unsigned short* ldsBase, int w, int lane) {
  const int rsub = lane >> 3;
  const int csw  = ((lane & 7) ^ rsub) << 3;  // elements
#pragma unroll
  for (int r = 0; r < 2; ++r) {
    __builtin_amdgcn_global_load_lds(
        (const __attribute__((address_space(1))) void*)(
            gsrc + (size_t)(r * 64 + w * 8 + rsub) * K_DIM + csw),
        (__attribute__((address_space(3))) void*)(ldsBase + r * 4096 + w * 512),
        16, 0, 0);
  }
}

#define DS_A(d, mh)                                                                 \
  do {                                                                              \
    _Pragma("unroll") for (int mi = 0; mi < 4; ++mi) {                              \
      _Pragma("unroll") for (int kk = 0; kk < 2; ++kk) {                            \
        a_frag[mi][kk] = *(const short8*)(ldsB + (d) * 65536 + aHalfByte +          \
                                          aRowByte + ((mh) * 4 + mi) * 2048 +       \
                                          kc[kk]);                                  \
      }                                                                             \
    }                                                                               \
  } while (0)

#define DS_B2(d, nh)                                                                \
  do {                                                                              \
    _Pragma("unroll") for (int ni = 0; ni < 2; ++ni) {                              \
      _Pragma("unroll") for (int kk = 0; kk < 2; ++kk) {                            \
        b_frag[(nh) * 2 + ni][kk] =                                                 \
            *(const short8*)(ldsB + (d) * 65536 + bHalfByte + bRowByte +            \
                             ((nh) * 2 + ni) * 2048 + kc[kk]);                      \
      }                                                                             \
    }                                                                               \
  } while (0)

#define MFMA_QUAD(mh, nh)                                                           \
  do {                                                                              \
    _Pragma("unroll") for (int mi = 0; mi < 4; ++mi) {                              \
      _Pragma("unroll") for (int ni = 0; ni < 2; ++ni) {                            \
        _Pragma("unroll") for (int kk = 0; kk < 2; ++kk) {                          \
          acc[(mh) * 4 + mi][(nh) * 2 + ni] =                                       \
              __builtin_amdgcn_mfma_f32_16x16x32_bf16(                              \
                  a_frag[mi][kk], b_frag[(nh) * 2 + ni][kk],                        \
                  acc[(mh) * 4 + mi][(nh) * 2 + ni], 0, 0, 0);                      \
        }                                                                           \
      }                                                                             \
    }                                                                               \
  } while (0)

#define LGKM0_FENCE()                                                               \
  do {                                                                              \
    asm volatile("s_waitcnt lgkmcnt(0)" ::: "memory");                              \
    __builtin_amdgcn_sched_barrier(0);                                              \
  } while (0)

#define VMC4() asm volatile("s_waitcnt vmcnt(4)" ::: "memory")

__global__ __launch_bounds__(512, 2) void qgemm8(const unsigned short* __restrict__ Abf,
                                                 const unsigned short* __restrict__ Wbf,
                                                 float* __restrict__ C) {
  __shared__ unsigned short lds[65536];  // 128 KiB

  // bijective XCD swizzle: 688 = 8 * 86
  int bid = blockIdx.x;
  {
    const int cpx = (NT_M * NT_N) >> 3;  // 86
    bid = (bid & 7) * cpx + (bid >> 3);
  }
  const int mt = bid / NT_N;
  const int nt = bid % NT_N;

  const int tid  = threadIdx.x;
  const int w    = tid >> 6;
  const int lane = tid & 63;
  const int l15  = lane & 15;
  const int l4   = lane >> 4;
  const int wr   = w >> 2;   // 0..1 -> 128 output rows
  const int wc   = w & 3;    // 0..3 -> 64 output cols

  const unsigned short* gA = Abf + (size_t)(mt * 256) * K_DIM;
  const unsigned short* gB = Wbf + (size_t)(nt * 256) * K_DIM;

  const char* ldsB = (const char*)lds;
  const unsigned aHalfByte = (unsigned)wr * 16384u;
  const unsigned bHalfByte = 32768u + (unsigned)(wc >> 1) * 16384u;
  const unsigned aRowByte  = (unsigned)l15 * 128u;
  const unsigned bRowByte  = (unsigned)((wc & 1) * 64 + l15) * 128u;
  const unsigned swz       = (unsigned)(l15 & 7) << 4;
  const unsigned kc[2]     = {((unsigned)(l4 * 16)) ^ swz,
                              ((unsigned)(64 + l4 * 16)) ^ swz};

  short8 a_frag[4][2];
  short8 b_frag[4][2];
  f32x4 acc[8][4];
#pragma unroll
  for (int m = 0; m < 8; ++m)
#pragma unroll
    for (int n = 0; n < 4; ++n) acc[m][n] = (f32x4)0.0f;

  // Prologue: B0(0) B1(0) A0(0) A1(0) B0(1) B1(1)  (12 loads/thread)
  stage_half(gB, lds + 16384, w, lane);
  stage_half(gB + (size_t)128 * K_DIM, lds + 24576, w, lane);
  stage_half(gA, lds + 0, w, lane);
  stage_half(gA + (size_t)128 * K_DIM, lds + 8192, w, lane);
  stage_half(gB + 64, lds + 49152, w, lane);
  stage_half(gB + (size_t)128 * K_DIM + 64, lds + 57344, w, lane);
  VMC4();  // d0 (B(0), A(0)) fully landed; B(1) still in flight
  __builtin_amdgcn_s_barrier();

#pragma unroll 1
  for (int i = 0; i < KT / 2; ++i) {
    const int t1 = 2 * i + 1;
    const int c2 = (2 * i + 2 < KT) ? 2 * i + 2 : KT - 1;  // clamped tail (dead writes)
    const int c3 = (2 * i + 3 < KT) ? 2 * i + 3 : KT - 1;

    // phA: reads d0 {A mh0, B nh0, B nh1}; stage A(t1)->d1; MFMA mh0 x all n
    DS_A(0, 0);
    DS_B2(0, 0);
    DS_B2(0, 1);
    __builtin_amdgcn_s_barrier();
    stage_half(gA + (size_t)t1 * 64, lds + 32768, w, lane);
    stage_half(gA + (size_t)128 * K_DIM + (size_t)t1 * 64, lds + 40960, w, lane);
    LGKM0_FENCE();
    __builtin_amdgcn_s_setprio(1);
    MFMA_QUAD(0, 0);
    MFMA_QUAD(0, 1);
    __builtin_amdgcn_s_setprio(0);

    // phB: reads {A mh1}; stage B(c2)->d0; MFMA mh1 x all n; VMC4; barrier
    // (retires A(t1) and B(prev c3) -> d1 fully resident after the barrier)
    DS_A(0, 1);
    __builtin_amdgcn_s_barrier();
    stage_half(gB + (size_t)c2 * 64, lds + 16384, w, lane);
    stage_half(gB + (size_t)128 * K_DIM + (size_t)c2 * 64, lds + 24576, w, lane);
    LGKM0_FENCE();
    __builtin_amdgcn_s_setprio(1);
    MFMA_QUAD(1, 1);
    MFMA_QUAD(1, 0);
    __builtin_amdgcn_s_setprio(0);
    VMC4();
    __builtin_amdgcn_s_barrier();

    // phC: reads d1 {A mh0, B nh0, B nh1}; stage A(c2)->d0; MFMA
    DS_A(1, 0);
    DS_B2(1, 0);
    DS_B2(1, 1);
    __builtin_amdgcn_s_barrier();
    stage_half(gA + (size_t)c2 * 64, lds + 0, w, lane);
    stage_half(gA + (size_t)128 * K_DIM + (size_t)c2 * 64, lds + 8192, w, lane);
    LGKM0_FENCE();
    __builtin_amdgcn_s_setprio(1);
    MFMA_QUAD(0, 0);
    MFMA_QUAD(0, 1);
    __builtin_amdgcn_s_setprio(0);

    // phD: reads {A mh1}; stage B(c3)->d1; MFMA; VMC4; barrier
    // (retires B(c2) and A(c2) -> d0 fully resident after the barrier)
    DS_A(1, 1);
    __builtin_amdgcn_s_barrier();
    stage_half(gB + (size_t)c3 * 64, lds + 49152, w, lane);
    stage_half(gB + (size_t)128 * K_DIM + (size_t)c3 * 64, lds + 57344, w, lane);
    LGKM0_FENCE();
    __builtin_amdgcn_s_setprio(1);
    MFMA_QUAD(1, 1);
    MFMA_QUAD(1, 0);
    __builtin_amdgcn_s_setprio(0);
    VMC4();
    __builtin_amdgcn_s_barrier();
  }

  // Epilogue: verified C/D map col=lane&15, row=(lane>>4)*4+reg
  const int grow = mt * 256 + wr * 128 + l4 * 4;
  const int gcol = nt * 256 + wc * 64 + l15;
#pragma unroll
  for (int ma = 0; ma < 8; ++ma)
#pragma unroll
    for (int n = 0; n < 4; ++n)
#pragma unroll
      for (int j = 0; j < 4; ++j)
        C[(size_t)(grow + ma * 16 + j) * N_DIM + (gcol + n * 16)] = acc[ma][n][j];
}

// ---- fallback: fused 128x128 kernel (only if ws too small) ----

__global__ __launch_bounds__(256) void qgemm_fused(const float* __restrict__ Ap,
                                                   const int* __restrict__ Bp,
                                                   const float* __restrict__ sp,
                                                   const float* __restrict__ zpp,
                                                   float* __restrict__ C) {
  __shared__ unsigned short As[128 * 64];
  __shared__ unsigned short Bs[128 * 64];
  int bid = blockIdx.x;
  {
    const int nwg = gridDim.x;
    if ((nwg & 7) == 0) bid = (bid & 7) * (nwg >> 3) + (bid >> 3);
  }
  const int mt = bid / (N_DIM / 128);
  const int nt = bid % (N_DIM / 128);
  const int tid = threadIdx.x, wave = tid >> 6, lane = tid & 63;
  const int l15 = lane & 15, l4 = lane >> 4, wr = wave >> 1, wcc = wave & 1;
  f32x4 acc[4][4];
#pragma unroll
  for (int m = 0; m < 4; ++m)
#pragma unroll
    for (int n = 0; n < 4; ++n) acc[m][n] = (f32x4)0.0f;
  const unsigned swz = (unsigned)(lane & 7) << 4;
  const unsigned aBase = (unsigned)(wr * 64 + l15) * 128;
  const unsigned bBase = (unsigned)(wcc * 64 + l15) * 128;
  const unsigned kc0 = ((unsigned)(l4 * 16)) ^ swz;
  const unsigned kc1 = ((unsigned)(64 + l4 * 16)) ^ swz;
  const char* AsB = (const char*)As;
  const char* BsB = (const char*)Bs;
  const float sc = *sp;
  const float nszp = -sc * (*zpp);
  for (int t = 0; t < K_DIM / 64; ++t) {
#pragma unroll
    for (int i = 0; i < 8; ++i) {
      const int c = i * 256 + tid;
      const int row = c >> 4, col = (c & 15) * 4;
      float4 v = *(const float4*)(Ap + (size_t)(mt * 128 + row) * K_DIM + t * 64 + col);
      ushort4 o = make_ushort4(f2bf(v.x), f2bf(v.y), f2bf(v.z), f2bf(v.w));
      const unsigned off = (unsigned)row * 128 +
                           (((unsigned)col * 2) ^ (((unsigned)(row & 7)) << 4));
      *(ushort4*)((char*)As + off) = o;
    }
#pragma unroll
    for (int i = 0; i < 8; ++i) {
      const int c = i * 256 + tid;
      const int row = c >> 4, col = (c & 15) * 4;
      int4 v = *(const int4*)(Bp + (size_t)(nt * 128 + row) * K_DIM + t * 64 + col);
      ushort4 o = make_ushort4(f2bf(fmaf(sc, (float)v.x, nszp)),
                               f2bf(fmaf(sc, (float)v.y, nszp)),
                               f2bf(fmaf(sc, (float)v.z, nszp)),
                               f2bf(fmaf(sc, (float)v.w, nszp)));
      const unsigned off = (unsigned)row * 128 +
                           (((unsigned)col * 2) ^ (((unsigned)(row & 7)) << 4));
      *(ushort4*)((char*)Bs + off) = o;
    }
    __syncthreads();
#pragma unroll
    for (int kk = 0; kk < 2; ++kk) {
      const unsigned kcx = kk ? kc1 : kc0;
      short8 af[4], bfr[4];
#pragma unroll
      for (int m = 0; m < 4; ++m) af[m] = *(const short8*)(AsB + aBase + m * 2048 + kcx);
#pragma unroll
      for (int n = 0; n < 4; ++n) bfr[n] = *(const short8*)(BsB + bBase + n * 2048 + kcx);
#pragma unroll
      for (int m = 0; m < 4; ++m)
#pragma unroll
        for (int n = 0; n < 4; ++n)
          acc[m][n] = __builtin_amdgcn_mfma_f32_16x16x32_bf16(af[m], bfr[n], acc[m][n], 0, 0, 0);
    }
    __syncthreads();
  }
  const int grow = mt * 128 + wr * 64 + l4 * 4;
  const int gcol = nt * 128 + wcc * 64 + l15;
#pragma unroll
  for (int m = 0; m < 4; ++m)
#pragma unroll
    for (int n = 0; n < 4; ++n)
#pragma unroll
      for (int j = 0; j < 4; ++j)
        C[(size_t)(grow + m * 16 + j) * N_DIM + (gcol + n * 16)] = acc[m][n][j];
}

extern "C" void kernel_launch(void* const* d_in, const int* in_sizes, int n_in,
                              void* d_out, int out_size, void* d_ws, size_t ws_size,
                              hipStream_t stream) {
  const float* x   = (const float*)d_in[0];
  const int*   wq  = (const int*)d_in[1];
  const float* sp  = (const float*)d_in[2];
  const float* zpp = (const float*)d_in[3];
  float* out = (float*)d_out;

  const size_t wbytes = (size_t)N_DIM * K_DIM * sizeof(unsigned short);
  const size_t xbytes = (size_t)M_DIM * K_DIM * sizeof(unsigned short);

  if (ws_size >= wbytes + xbytes) {
    unsigned short* wb = (unsigned short*)d_ws;
    unsigned short* xb = (unsigned short*)((char*)d_ws + wbytes);
    cvt_w_kernel<<<2048, 256, 0, stream>>>(wq, wb, sp, zpp,
                                           (int)((size_t)N_DIM * K_DIM / 4));
    cvt_x_kernel<<<2048, 256, 0, stream>>>(x, xb,
                                           (int)((size_t)M_DIM * K_DIM / 4));
    qgemm8<<<NT_M * NT_N, 512, 0, stream>>>(xb, wb, out);
  } else {
    qgemm_fused<<<(M_DIM / 128) * (N_DIM / 128), 256, 0, stream>>>(x, wq, sp, zpp, out);
  }
}

// Round 4
// 255.178 us; speedup vs baseline: 1.5770x; 1.5770x over previous
//
#include <hip/hip_runtime.h>

// QuantizedLinear: out[M=4096, N=11008] = x[M,K=4096] @ (s*(q-zp))[N,K]^T
// Round 4: i8 MFMA path. w is exactly int8-valued -> lossless i8. x quantized
// per-row (scale=absmax/127); out = s*sx[m]*(xq.q^T) - s*zp*rowsum_x[m].
// GEMM: 256x256 tile, BK=128 bytes -> byte-identical LDS geometry to the
// verified bf16 kernel (16KB halves, 128B row stride, XOR swizzle, vmcnt(4)
// chain), mfma_i32_16x16x64_i8, 16 iterations (was 32).

#define M_DIM 4096
#define N_DIM 11008
#define K_DIM 4096
#define KT8 32             // K tiles of BK=128 (bytes)
#define NT_N 43            // N_DIM / 256
#define NT_M 16            // M_DIM / 256

typedef __attribute__((ext_vector_type(4))) int i32x4;
typedef __attribute__((ext_vector_type(4))) float f32x4;
typedef __attribute__((ext_vector_type(8))) short short8;

__device__ inline unsigned short f2bf(float f) {
  unsigned int u = __float_as_uint(f);
  u += 0x7FFFu + ((u >> 16) & 1u);
  return (unsigned short)(u >> 16);
}

// ---- w: int32 -> int8 (lossless narrowing copy) ----
__global__ __launch_bounds__(256) void cvt_w_i8(const int* __restrict__ q,
                                                int4* __restrict__ wb, int n16) {
  int stride = gridDim.x * blockDim.x;
  for (int i = blockIdx.x * blockDim.x + threadIdx.x; i < n16; i += stride) {
    const int4* s = (const int4*)q + (size_t)i * 4;
    int4 a = s[0], b = s[1], c = s[2], d = s[3];
    int4 o;
    o.x = (a.x & 0xff) | ((a.y & 0xff) << 8) | ((a.z & 0xff) << 16) | ((a.w & 0xff) << 24);
    o.y = (b.x & 0xff) | ((b.y & 0xff) << 8) | ((b.z & 0xff) << 16) | ((b.w & 0xff) << 24);
    o.z = (c.x & 0xff) | ((c.y & 0xff) << 8) | ((c.z & 0xff) << 16) | ((c.w & 0xff) << 24);
    o.w = (d.x & 0xff) | ((d.y & 0xff) << 8) | ((d.z & 0xff) << 16) | ((d.w & 0xff) << 24);
    wb[i] = o;
  }
}

// ---- x: fp32 -> per-row i8 + scale + fp32 rowsum; one block per row ----
__global__ __launch_bounds__(256) void cvt_x_i8(const float* __restrict__ x,
                                                int4* __restrict__ xb,
                                                float* __restrict__ sx,
                                                float* __restrict__ rs) {
  const int row = blockIdx.x;
  const float* xr = x + (size_t)row * K_DIM;
  const int t = threadIdx.x;
  float4 v[4];
  float amax = 0.f, sum = 0.f;
#pragma unroll
  for (int j = 0; j < 4; ++j) {
    v[j] = *(const float4*)(xr + t * 16 + j * 4);
    amax = fmaxf(amax, fmaxf(fmaxf(fabsf(v[j].x), fabsf(v[j].y)),
                             fmaxf(fabsf(v[j].z), fabsf(v[j].w))));
    sum += (v[j].x + v[j].y) + (v[j].z + v[j].w);
  }
#pragma unroll
  for (int off = 1; off < 64; off <<= 1) {
    amax = fmaxf(amax, __shfl_xor(amax, off, 64));
    sum += __shfl_xor(sum, off, 64);
  }
  __shared__ float smx[4], sms[4];
  const int wv = t >> 6, ln = t & 63;
  if (ln == 0) { smx[wv] = amax; sms[wv] = sum; }
  __syncthreads();
  const float gmax = fmaxf(fmaxf(smx[0], smx[1]), fmaxf(smx[2], smx[3]));
  const float gsum = (sms[0] + sms[1]) + (sms[2] + sms[3]);
  const float gm = fmaxf(gmax, 1e-30f);
  const float qs = 127.f / gm;
  int b[16];
#pragma unroll
  for (int j = 0; j < 4; ++j) {
    b[j * 4 + 0] = (int)rintf(v[j].x * qs);
    b[j * 4 + 1] = (int)rintf(v[j].y * qs);
    b[j * 4 + 2] = (int)rintf(v[j].z * qs);
    b[j * 4 + 3] = (int)rintf(v[j].w * qs);
  }
  int4 o;
  o.x = (b[0] & 0xff) | ((b[1] & 0xff) << 8) | ((b[2] & 0xff) << 16) | ((b[3] & 0xff) << 24);
  o.y = (b[4] & 0xff) | ((b[5] & 0xff) << 8) | ((b[6] & 0xff) << 16) | ((b[7] & 0xff) << 24);
  o.z = (b[8] & 0xff) | ((b[9] & 0xff) << 8) | ((b[10] & 0xff) << 16) | ((b[11] & 0xff) << 24);
  o.w = (b[12] & 0xff) | ((b[13] & 0xff) << 8) | ((b[14] & 0xff) << 16) | ((b[15] & 0xff) << 24);
  xb[((size_t)row * K_DIM >> 4) + t] = o;
  if (t == 0) { sx[row] = gm / 127.f; rs[row] = gsum; }
}

// ---- i8 GEMM, 256x256, BK=128 bytes, 4-phase counted-vmcnt pipeline ----
// LDS (bytes): A(d,h) = d*65536 + h*16384 ; B(d,h) = d*65536 + 32768 + h*16384
// Half-tile = 128 rows x 128 bytes = 16KB. Swizzle: elem (r,kbyte) at byte
// r*128 + (kbyte ^ ((r&7)<<4)); staged linearly via global_load_lds with the
// inverse-swizzled global source (verified involution, rounds 1-3).

__device__ __forceinline__ void stage_half(const char* __restrict__ gsrc,
                                           char* ldsBase, int w, int lane) {
  const int rsub = lane >> 3;
  const int csw  = ((lane & 7) ^ rsub) << 4;  // bytes
#pragma unroll
  for (int r = 0; r < 2; ++r) {
    __builtin_amdgcn_global_load_lds(
        (const __attribute__((address_space(1))) void*)(
            gsrc + (size_t)(r * 64 + w * 8 + rsub) * K_DIM + csw),
        (__attribute__((address_space(3))) void*)(ldsBase + r * 8192 + w * 1024),
        16, 0, 0);
  }
}

#define DS_A(d, mh)                                                                 \
  do {                                                                              \
    _Pragma("unroll") for (int mi = 0; mi < 4; ++mi) {                              \
      _Pragma("unroll") for (int kk = 0; kk < 2; ++kk) {                            \
        a_frag[mi][kk] = *(const i32x4*)(ldsB + (d) * 65536 + aHalf + aRow +        \
                                         ((mh) * 4 + mi) * 2048 + kc[kk]);          \
      }                                                                             \
    }                                                                               \
  } while (0)

#define DS_B2(d, nh)                                                                \
  do {                                                                              \
    _Pragma("unroll") for (int ni = 0; ni < 2; ++ni) {                              \
      _Pragma("unroll") for (int kk = 0; kk < 2; ++kk) {                            \
        b_frag[(nh) * 2 + ni][kk] =                                                 \
            *(const i32x4*)(ldsB + (d) * 65536 + bHalf + bRow +                     \
                            ((nh) * 2 + ni) * 2048 + kc[kk]);                       \
      }                                                                             \
    }                                                                               \
  } while (0)

#define MFMA_QUAD(mh, nh)                                                           \
  do {                                                                              \
    _Pragma("unroll") for (int mi = 0; mi < 4; ++mi) {                              \
      _Pragma("unroll") for (int ni = 0; ni < 2; ++ni) {                            \
        _Pragma("unroll") for (int kk = 0; kk < 2; ++kk) {                          \
          acc[(mh) * 4 + mi][(nh) * 2 + ni] =                                       \
              __builtin_amdgcn_mfma_i32_16x16x64_i8(                                \
                  a_frag[mi][kk], b_frag[(nh) * 2 + ni][kk],                        \
                  acc[(mh) * 4 + mi][(nh) * 2 + ni], 0, 0, 0);                      \
        }                                                                           \
      }                                                                             \
    }                                                                               \
  } while (0)

#define LGKM0_FENCE()                                                               \
  do {                                                                              \
    asm volatile("s_waitcnt lgkmcnt(0)" ::: "memory");                              \
    __builtin_amdgcn_sched_barrier(0);                                              \
  } while (0)

#define VMC4() asm volatile("s_waitcnt vmcnt(4)" ::: "memory")

__global__ __launch_bounds__(512, 2) void qgemm_i8(const char* __restrict__ Ai8,
                                                   const char* __restrict__ Wi8,
                                                   const float* __restrict__ sx,
                                                   const float* __restrict__ rs,
                                                   const float* __restrict__ sp,
                                                   const float* __restrict__ zpp,
                                                   float* __restrict__ C) {
  __shared__ char lds[131072];  // 128 KiB

  // bijective XCD swizzle: 688 = 8 * 86
  int bid = blockIdx.x;
  {
    const int cpx = (NT_M * NT_N) >> 3;  // 86
    bid = (bid & 7) * cpx + (bid >> 3);
  }
  const int mt = bid / NT_N;
  const int nt = bid % NT_N;

  const int tid  = threadIdx.x;
  const int w    = tid >> 6;
  const int lane = tid & 63;
  const int l15  = lane & 15;
  const int l4   = lane >> 4;
  const int wr   = w >> 2;   // 0..1 -> 128 output rows
  const int wc   = w & 3;    // 0..3 -> 64 output cols

  const char* gA = Ai8 + (size_t)(mt * 256) * K_DIM;
  const char* gB = Wi8 + (size_t)(nt * 256) * K_DIM;

  const char* ldsB = (const char*)lds;
  const unsigned aHalf = (unsigned)wr * 16384u;
  const unsigned bHalf = 32768u + (unsigned)(wc >> 1) * 16384u;
  const unsigned aRow  = (unsigned)l15 * 128u;
  const unsigned bRow  = (unsigned)((wc & 1) * 64 + l15) * 128u;
  const unsigned swz   = (unsigned)(l15 & 7) << 4;
  const unsigned kc[2] = {((unsigned)(l4 * 16)) ^ swz,
                          ((unsigned)(64 + l4 * 16)) ^ swz};

  i32x4 a_frag[4][2];
  i32x4 b_frag[4][2];
  i32x4 acc[8][4];
#pragma unroll
  for (int m = 0; m < 8; ++m)
#pragma unroll
    for (int n = 0; n < 4; ++n) acc[m][n] = (i32x4)0;

  // Prologue: B0(0) B1(0) A0(0) A1(0) B0(1) B1(1)  (12 loads/thread)
  stage_half(gB, lds + 32768, w, lane);
  stage_half(gB + (size_t)128 * K_DIM, lds + 49152, w, lane);
  stage_half(gA, lds + 0, w, lane);
  stage_half(gA + (size_t)128 * K_DIM, lds + 16384, w, lane);
  stage_half(gB + 128, lds + 98304, w, lane);
  stage_half(gB + (size_t)128 * K_DIM + 128, lds + 114688, w, lane);
  VMC4();  // d0 (B(0), A(0)) landed; B(1) still in flight
  __builtin_amdgcn_s_barrier();

#pragma unroll 1
  for (int i = 0; i < KT8 / 2; ++i) {
    const int t1 = 2 * i + 1;
    const int c2 = (2 * i + 2 < KT8) ? 2 * i + 2 : KT8 - 1;  // clamped tail
    const int c3 = (2 * i + 3 < KT8) ? 2 * i + 3 : KT8 - 1;

    // phA: reads d0 {A mh0, B all}; stage A(t1)->d1
    DS_A(0, 0);
    DS_B2(0, 0);
    DS_B2(0, 1);
    __builtin_amdgcn_s_barrier();
    stage_half(gA + (size_t)t1 * 128, lds + 65536, w, lane);
    stage_half(gA + (size_t)128 * K_DIM + (size_t)t1 * 128, lds + 81920, w, lane);
    LGKM0_FENCE();
    __builtin_amdgcn_s_setprio(1);
    MFMA_QUAD(0, 0);
    MFMA_QUAD(0, 1);
    __builtin_amdgcn_s_setprio(0);

    // phB: reads d0 {A mh1}; stage B(c2)->d0; VMC4 retires B(t1),A(t1) -> d1 ready
    DS_A(0, 1);
    __builtin_amdgcn_s_barrier();
    stage_half(gB + (size_t)c2 * 128, lds + 32768, w, lane);
    stage_half(gB + (size_t)128 * K_DIM + (size_t)c2 * 128, lds + 49152, w, lane);
    LGKM0_FENCE();
    __builtin_amdgcn_s_setprio(1);
    MFMA_QUAD(1, 1);
    MFMA_QUAD(1, 0);
    __builtin_amdgcn_s_setprio(0);
    VMC4();
    __builtin_amdgcn_s_barrier();

    // phC: reads d1 {A mh0, B all}; stage A(c2)->d0
    DS_A(1, 0);
    DS_B2(1, 0);
    DS_B2(1, 1);
    __builtin_amdgcn_s_barrier();
    stage_half(gA + (size_t)c2 * 128, lds + 0, w, lane);
    stage_half(gA + (size_t)128 * K_DIM + (size_t)c2 * 128, lds + 16384, w, lane);
    LGKM0_FENCE();
    __builtin_amdgcn_s_setprio(1);
    MFMA_QUAD(0, 0);
    MFMA_QUAD(0, 1);
    __builtin_amdgcn_s_setprio(0);

    // phD: reads d1 {A mh1}; stage B(c3)->d1; VMC4 retires B(c2),A(c2) -> d0 ready
    DS_A(1, 1);
    __builtin_amdgcn_s_barrier();
    stage_half(gB + (size_t)c3 * 128, lds + 98304, w, lane);
    stage_half(gB + (size_t)128 * K_DIM + (size_t)c3 * 128, lds + 114688, w, lane);
    LGKM0_FENCE();
    __builtin_amdgcn_s_setprio(1);
    MFMA_QUAD(1, 1);
    MFMA_QUAD(1, 0);
    __builtin_amdgcn_s_setprio(0);
    VMC4();
    __builtin_amdgcn_s_barrier();
  }

  // Epilogue: C/D map col=lane&15, row=(lane>>4)*4+reg (shape-determined,
  // dtype-independent per m121-m128). out = s*sx[m]*acc - s*zp*rs[m].
  const float s   = *sp;
  const float szp = s * (*zpp);
  const int grow = mt * 256 + wr * 128 + l4 * 4;
  const int gcol = nt * 256 + wc * 64 + l15;
#pragma unroll
  for (int ma = 0; ma < 8; ++ma) {
#pragma unroll
    for (int j = 0; j < 4; ++j) {
      const int m = grow + ma * 16 + j;
      const float alpha = s * sx[m];
      const float beta  = szp * rs[m];
#pragma unroll
      for (int n = 0; n < 4; ++n)
        C[(size_t)m * N_DIM + (gcol + n * 16)] =
            fmaf(alpha, (float)acc[ma][n][j], -beta);
    }
  }
}

// ---- fallback: fused bf16 128x128 kernel (only if ws too small) ----

typedef __attribute__((ext_vector_type(8))) short short8_t;

__global__ __launch_bounds__(256) void qgemm_fused(const float* __restrict__ Ap,
                                                   const int* __restrict__ Bp,
                                                   const float* __restrict__ sp,
                                                   const float* __restrict__ zpp,
                                                   float* __restrict__ C) {
  __shared__ unsigned short As[128 * 64];
  __shared__ unsigned short Bs[128 * 64];
  int bid = blockIdx.x;
  {
    const int nwg = gridDim.x;
    if ((nwg & 7) == 0) bid = (bid & 7) * (nwg >> 3) + (bid >> 3);
  }
  const int mt = bid / (N_DIM / 128);
  const int nt = bid % (N_DIM / 128);
  const int tid = threadIdx.x, wave = tid >> 6, lane = tid & 63;
  const int l15 = lane & 15, l4 = lane >> 4, wr = wave >> 1, wcc = wave & 1;
  f32x4 acc[4][4];
#pragma unroll
  for (int m = 0; m < 4; ++m)
#pragma unroll
    for (int n = 0; n < 4; ++n) acc[m][n] = (f32x4)0.0f;
  const unsigned swz = (unsigned)(lane & 7) << 4;
  const unsigned aBase = (unsigned)(wr * 64 + l15) * 128;
  const unsigned bBase = (unsigned)(wcc * 64 + l15) * 128;
  const unsigned kc0 = ((unsigned)(l4 * 16)) ^ swz;
  const unsigned kc1 = ((unsigned)(64 + l4 * 16)) ^ swz;
  const char* AsB = (const char*)As;
  const char* BsB = (const char*)Bs;
  const float sc = *sp;
  const float nszp = -sc * (*zpp);
  for (int t = 0; t < K_DIM / 64; ++t) {
#pragma unroll
    for (int i = 0; i < 8; ++i) {
      const int c = i * 256 + tid;
      const int row = c >> 4, col = (c & 15) * 4;
      float4 v = *(const float4*)(Ap + (size_t)(mt * 128 + row) * K_DIM + t * 64 + col);
      ushort4 o = make_ushort4(f2bf(v.x), f2bf(v.y), f2bf(v.z), f2bf(v.w));
      const unsigned off = (unsigned)row * 128 +
                           (((unsigned)col * 2) ^ (((unsigned)(row & 7)) << 4));
      *(ushort4*)((char*)As + off) = o;
    }
#pragma unroll
    for (int i = 0; i < 8; ++i) {
      const int c = i * 256 + tid;
      const int row = c >> 4, col = (c & 15) * 4;
      int4 v = *(const int4*)(Bp + (size_t)(nt * 128 + row) * K_DIM + t * 64 + col);
      ushort4 o = make_ushort4(f2bf(fmaf(sc, (float)v.x, nszp)),
                               f2bf(fmaf(sc, (float)v.y, nszp)),
                               f2bf(fmaf(sc, (float)v.z, nszp)),
                               f2bf(fmaf(sc, (float)v.w, nszp)));
      const unsigned off = (unsigned)row * 128 +
                           (((unsigned)col * 2) ^ (((unsigned)(row & 7)) << 4));
      *(ushort4*)((char*)Bs + off) = o;
    }
    __syncthreads();
#pragma unroll
    for (int kk = 0; kk < 2; ++kk) {
      const unsigned kcx = kk ? kc1 : kc0;
      short8_t af[4], bfr[4];
#pragma unroll
      for (int m = 0; m < 4; ++m) af[m] = *(const short8_t*)(AsB + aBase + m * 2048 + kcx);
#pragma unroll
      for (int n = 0; n < 4; ++n) bfr[n] = *(const short8_t*)(BsB + bBase + n * 2048 + kcx);
#pragma unroll
      for (int m = 0; m < 4; ++m)
#pragma unroll
        for (int n = 0; n < 4; ++n)
          acc[m][n] = __builtin_amdgcn_mfma_f32_16x16x32_bf16(af[m], bfr[n], acc[m][n], 0, 0, 0);
    }
    __syncthreads();
  }
  const int grow = mt * 128 + wr * 64 + l4 * 4;
  const int gcol = nt * 128 + wcc * 64 + l15;
#pragma unroll
  for (int m = 0; m < 4; ++m)
#pragma unroll
    for (int n = 0; n < 4; ++n)
#pragma unroll
      for (int j = 0; j < 4; ++j)
        C[(size_t)(grow + m * 16 + j) * N_DIM + (gcol + n * 16)] = acc[m][n][j];
}

extern "C" void kernel_launch(void* const* d_in, const int* in_sizes, int n_in,
                              void* d_out, int out_size, void* d_ws, size_t ws_size,
                              hipStream_t stream) {
  const float* x   = (const float*)d_in[0];
  const int*   wq  = (const int*)d_in[1];
  const float* sp  = (const float*)d_in[2];
  const float* zpp = (const float*)d_in[3];
  float* out = (float*)d_out;

  const size_t wbytes = (size_t)N_DIM * K_DIM;        // 45,088,768 (i8)
  const size_t xbytes = (size_t)M_DIM * K_DIM;        // 16,777,216 (i8)
  const size_t need   = wbytes + xbytes + 2 * (size_t)M_DIM * sizeof(float);

  if (ws_size >= need) {
    char*  wb = (char*)d_ws;
    char*  xb = (char*)d_ws + wbytes;
    float* sx = (float*)((char*)d_ws + wbytes + xbytes);
    float* rs = sx + M_DIM;
    cvt_w_i8<<<2048, 256, 0, stream>>>(wq, (int4*)wb,
                                       (int)((size_t)N_DIM * K_DIM / 16));
    cvt_x_i8<<<M_DIM, 256, 0, stream>>>(x, (int4*)xb, sx, rs);
    qgemm_i8<<<NT_M * NT_N, 512, 0, stream>>>(xb, wb, sx, rs, sp, zpp, out);
  } else {
    qgemm_fused<<<(M_DIM / 128) * (N_DIM / 128), 256, 0, stream>>>(x, wq, sp, zpp, out);
  }
}